// Round 13
// baseline (263.072 us; speedup 1.0000x reference)
//
#include <hip/hip_runtime.h>
#include <hip/hip_bf16.h>

constexpr int NN  = 50000;
constexpr int NN2 = 50048;
constexpr int NE  = 800000;
constexpr int SCAN_B = 1024;
constexpr int NB = (NN + SCAN_B - 1) / SCAN_B;    // 49 scan blocks
constexpr int GB = (NN + 63) / 64;                // 782 gemm blocks per chunk
constexpr int RANK_BASE = 2 * GB;                 // first rank block in fused kernel
constexpr int RANK_BLOCKS = (NE + 255) / 256;     // 3125

__device__ __forceinline__ float bfu_to_f(unsigned int u16) {
    return __uint_as_float(u16 << 16);
}
__device__ __forceinline__ float bflo(unsigned int u) { return __uint_as_float(u << 16); }
__device__ __forceinline__ float bfhi(unsigned int u) { return __uint_as_float(u & 0xffff0000u); }
__device__ __forceinline__ unsigned short f_to_bfu(float f) {
    unsigned int u = __float_as_uint(f);
    return (unsigned short)((u + 0x7fffu + ((u >> 16) & 1u)) >> 16);
}
__device__ __forceinline__ unsigned int f2_to_bfu2(float a, float b) {
    return (unsigned int)f_to_bfu(a) | ((unsigned int)f_to_bfu(b) << 16);
}

// ---------- fused: layer-1 GEMM (2 chunks, bf16-staged LDS) + replicated rank ----------
// blocks [0, 2GB)         : gemm chunks (wc0 = 0 / 64)
// blocks [2GB, 2GB+3125)  : rank — pos[e] = atomicAdd(cnt[blockIdx%8][dst[e]], 1)
__global__ __launch_bounds__(256) void fused_gemm1_rank(
        const float* __restrict__ X, const float* __restrict__ W,
        unsigned short* __restrict__ H,
        const int* __restrict__ dst, int* __restrict__ cnt, int* __restrict__ pos) {
    constexpr int K = 128, N = 64, KT = 64;
    constexpr int XS = K + 4;          // bf16 row stride: 132 shorts = 66 words
    constexpr int CP = N / 4, RPT = 4;

    __shared__ unsigned short Xs[64 * XS];   // 16.9 KB
    __shared__ unsigned short Ws[KT * N];    //  8.2 KB  -> total ~25 KB, 6 blk/CU

    const int bid = blockIdx.x;
    if (bid >= RANK_BASE) {
        int e = (bid - RANK_BASE) * 256 + threadIdx.x;
        if (e < NE) {
            int rep = bid & 7;   // ~XCD id (round-robin dispatch heuristic)
            pos[e] = atomicAdd(&cnt[rep * NN2 + dst[e]], 1);
        }
        return;
    }

    const int chunk = (bid < GB) ? 0 : 1;
    const int wc0 = chunk * 64;
    const int tid = threadIdx.x;
    const int rb  = (bid - chunk * GB) * 64;
    const int cp  = tid % CP;
    const int rg  = tid / CP;
    const int r0  = rg * RPT;

    // stage X rows [rb, rb+64) as bf16, float4 -> ushort4
    {
        const float4* Xv = reinterpret_cast<const float4*>(X + (size_t)rb * K);
        constexpr int VPR = K / 4;   // 32 float4 per row
        for (int i = tid; i < 64 * VPR; i += 256) {
            int r = i / VPR, j = i - r * VPR;
            float4 v = make_float4(0.f, 0.f, 0.f, 0.f);
            if (rb + r < NN) v = Xv[i];
            unsigned int* o = reinterpret_cast<unsigned int*>(Xs + r * XS + j * 4);
            o[0] = f2_to_bfu2(v.x, v.y);
            o[1] = f2_to_bfu2(v.z, v.w);
        }
    }

    float4 acc[RPT];
#pragma unroll
    for (int i = 0; i < RPT; i++) acc[i] = make_float4(0.f, 0.f, 0.f, 0.f);

    for (int kt = 0; kt < K; kt += KT) {
        // stage W tile [kt,kt+64) x [wc0,wc0+64) as bf16
        {
            const float4* Wv = reinterpret_cast<const float4*>(W);
            constexpr int VPW = N / 4, VWR = 128 / 4;
            const int cv0 = wc0 / 4;
            for (int i = tid; i < KT * VPW; i += 256) {
                int k = i / VPW, j = i - k * VPW;
                float4 v = Wv[(kt + k) * VWR + cv0 + j];
                unsigned int* o = reinterpret_cast<unsigned int*>(Ws + k * N + j * 4);
                o[0] = f2_to_bfu2(v.x, v.y);
                o[1] = f2_to_bfu2(v.z, v.w);
            }
        }
        __syncthreads();

#pragma unroll 4
        for (int k4 = 0; k4 < KT; k4 += 4) {
            uint2 xu[RPT];
#pragma unroll
            for (int i = 0; i < RPT; i++)
                xu[i] = *reinterpret_cast<const uint2*>(Xs + (r0 + i) * XS + kt + k4);
            uint2 wu[4];
#pragma unroll
            for (int j = 0; j < 4; j++)
                wu[j] = *reinterpret_cast<const uint2*>(Ws + (k4 + j) * N + cp * 4);
            float wf[4][4];
#pragma unroll
            for (int j = 0; j < 4; j++) {
                wf[j][0] = bflo(wu[j].x); wf[j][1] = bfhi(wu[j].x);
                wf[j][2] = bflo(wu[j].y); wf[j][3] = bfhi(wu[j].y);
            }
#pragma unroll
            for (int i = 0; i < RPT; i++) {
                float xf[4];
                xf[0] = bflo(xu[i].x); xf[1] = bfhi(xu[i].x);
                xf[2] = bflo(xu[i].y); xf[3] = bfhi(xu[i].y);
#pragma unroll
                for (int j = 0; j < 4; j++) {
                    acc[i].x += xf[j] * wf[j][0];
                    acc[i].y += xf[j] * wf[j][1];
                    acc[i].z += xf[j] * wf[j][2];
                    acc[i].w += xf[j] * wf[j][3];
                }
            }
        }
        __syncthreads();
    }

#pragma unroll
    for (int i = 0; i < RPT; i++) {
        int row = rb + r0 + i;
        if (row < NN) {
            ushort4 o;
            o.x = f_to_bfu(acc[i].x); o.y = f_to_bfu(acc[i].y);
            o.z = f_to_bfu(acc[i].z); o.w = f_to_bfu(acc[i].w);
            *reinterpret_cast<ushort4*>(H + (size_t)row * 128 + wc0 + 4 * cp) = o;
        }
    }
}

// ---------- reduce replicas: deg, dinv, per-replica offsets, scan partials ----------
__global__ __launch_bounds__(256) void reduce_kernel(const int* __restrict__ cnt,
                                                     int* __restrict__ deg,
                                                     int* __restrict__ roff,
                                                     float* __restrict__ dinv,
                                                     int* __restrict__ bsum, int n) {
    __shared__ int wred[4];
    const int tid = threadIdx.x, lane = tid & 63, wid = tid >> 6;
    int t0 = blockIdx.x * SCAN_B + tid * 4;
    int local = 0;
#pragma unroll
    for (int j = 0; j < 4; j++) {
        int t = t0 + j;
        if (t < n) {
            int acc = 0;
#pragma unroll
            for (int r = 0; r < 8; r++) {
                roff[r * NN2 + t] = acc;
                acc += cnt[r * NN2 + t];
            }
            deg[t] = acc;
            dinv[t] = rsqrtf((float)acc + 1.0f);
            local += acc;
        }
    }
#pragma unroll
    for (int off = 32; off >= 1; off >>= 1) local += __shfl_xor(local, off);
    if (lane == 0) wred[wid] = local;
    __syncthreads();
    if (tid == 0) bsum[blockIdx.x] = wred[0] + wred[1] + wred[2] + wred[3];
}

// ---------- one-wave exclusive scan of block sums ----------
__global__ __launch_bounds__(64) void scan_tops(const int* __restrict__ bsum,
                                                int* __restrict__ boff,
                                                int* __restrict__ total_out, int nb) {
    int lane = threadIdx.x;
    int v = (lane < nb) ? bsum[lane] : 0;
    int incl = v;
#pragma unroll
    for (int off = 1; off < 64; off <<= 1) {
        int t = __shfl_up(incl, off, 64);
        if (lane >= off) incl += t;
    }
    if (lane < nb) boff[lane] = incl - v;
    if (lane == 63) total_out[0] = incl;
}

// ---------- per-block scan + global offset -> rowptr ----------
__global__ __launch_bounds__(256) void scan_fill(const int* __restrict__ deg,
                                                 const int* __restrict__ boff,
                                                 int* __restrict__ rowptr, int n) {
    __shared__ int wsum[4];
    __shared__ int woff[4];
    const int tid = threadIdx.x, lane = tid & 63, wid = tid >> 6;
    int idx = blockIdx.x * SCAN_B + tid * 4;
    int v0 = (idx + 0 < n) ? deg[idx + 0] : 0;
    int v1 = (idx + 1 < n) ? deg[idx + 1] : 0;
    int v2 = (idx + 2 < n) ? deg[idx + 2] : 0;
    int v3 = (idx + 3 < n) ? deg[idx + 3] : 0;
    int local = v0 + v1 + v2 + v3;
    int incl = local;
#pragma unroll
    for (int off = 1; off < 64; off <<= 1) {
        int t = __shfl_up(incl, off, 64);
        if (lane >= off) incl += t;
    }
    if (lane == 63) wsum[wid] = incl;
    __syncthreads();
    if (tid == 0) {
        int acc = boff[blockIdx.x];
        for (int w = 0; w < 4; w++) { woff[w] = acc; acc += wsum[w]; }
    }
    __syncthreads();
    int p = woff[wid] + (incl - local);
    if (idx + 0 < n) rowptr[idx + 0] = p; p += v0;
    if (idx + 1 < n) rowptr[idx + 1] = p; p += v1;
    if (idx + 2 < n) rowptr[idx + 2] = p; p += v2;
    if (idx + 3 < n) rowptr[idx + 3] = p;
}

// ---------- place: srcs[rowptr[t] + roff[rep][t] + pos[e]] = src[e] ----------
__global__ __launch_bounds__(256) void place_kernel(const int* __restrict__ src,
                                                    const int* __restrict__ dst,
                                                    const int* __restrict__ rowptr,
                                                    const int* __restrict__ roff,
                                                    const int* __restrict__ pos,
                                                    unsigned short* __restrict__ srcs,
                                                    int E) {
    int e = blockIdx.x * 256 + threadIdx.x;
    if (e >= E) return;
    int t = dst[e];
    int rep = (RANK_BASE + (e >> 8)) & 7;   // must match fused rank block mapping
    srcs[rowptr[t] + roff[rep * NN2 + t] + pos[e]] = (unsigned short)src[e];
}

// ---------- GEMM (standalone, layer 2, fp32 LDS) ----------
template <int K, int N, int WN, int OS>
__global__ __launch_bounds__(256) void gemm_kernel(const float* __restrict__ X,
                                                   const float* __restrict__ W,
                                                   int wc0, int oc0,
                                                   unsigned short* __restrict__ H, int M) {
    constexpr int ROWS = 64, KT = 64, XS = K + 4;
    constexpr int CP = N / 4, NRG = 256 / CP, RPT = ROWS / NRG;

    __shared__ float Xs[ROWS * XS];
    __shared__ float Ws[KT * N];

    const int tid = threadIdx.x;
    const int rb  = blockIdx.x * ROWS;
    const int cp  = tid % CP;
    const int rg  = tid / CP;
    const int r0  = rg * RPT;

    {
        const float4* Xv  = reinterpret_cast<const float4*>(X + (size_t)rb * K);
        float4*       Xsv = reinterpret_cast<float4*>(Xs);
        constexpr int VPR = K / 4;
        for (int i = tid; i < ROWS * VPR; i += 256) {
            int r = i / VPR, j = i - r * VPR;
            float4 v = make_float4(0.f, 0.f, 0.f, 0.f);
            if (rb + r < M) v = Xv[i];
            Xsv[r * (XS / 4) + j] = v;
        }
    }

    float4 acc[RPT];
#pragma unroll
    for (int i = 0; i < RPT; i++) acc[i] = make_float4(0.f, 0.f, 0.f, 0.f);

    for (int kt = 0; kt < K; kt += KT) {
        {
            const float4* Wv  = reinterpret_cast<const float4*>(W);
            float4*       Wsv = reinterpret_cast<float4*>(Ws);
            constexpr int VPW = N / 4, VWR = WN / 4;
            const int cv0 = wc0 / 4;
            for (int i = tid; i < KT * VPW; i += 256) {
                int k = i / VPW, j = i - k * VPW;
                Wsv[i] = Wv[(kt + k) * VWR + cv0 + j];
            }
        }
        __syncthreads();

        const float4* Xs4 = reinterpret_cast<const float4*>(Xs);
        const float4* Ws4 = reinterpret_cast<const float4*>(Ws);
#pragma unroll 4
        for (int k4 = 0; k4 < KT; k4 += 4) {
            float4 xq[RPT];
#pragma unroll
            for (int i = 0; i < RPT; i++)
                xq[i] = Xs4[(r0 + i) * (XS / 4) + (kt + k4) / 4];
            float4 wq[4];
#pragma unroll
            for (int j = 0; j < 4; j++) wq[j] = Ws4[(k4 + j) * CP + cp];
#pragma unroll
            for (int j = 0; j < 4; j++) {
#pragma unroll
                for (int i = 0; i < RPT; i++) {
                    float xx = reinterpret_cast<const float*>(&xq[i])[j];
                    acc[i].x += xx * wq[j].x;
                    acc[i].y += xx * wq[j].y;
                    acc[i].z += xx * wq[j].z;
                    acc[i].w += xx * wq[j].w;
                }
            }
        }
        __syncthreads();
    }

#pragma unroll
    for (int i = 0; i < RPT; i++) {
        int row = rb + r0 + i;
        if (row < M) {
            ushort4 o;
            o.x = f_to_bfu(acc[i].x); o.y = f_to_bfu(acc[i].y);
            o.z = f_to_bfu(acc[i].z); o.w = f_to_bfu(acc[i].w);
            *reinterpret_cast<ushort4*>(H + (size_t)row * OS + oc0 + 4 * cp) = o;
        }
    }
}

// ---------- fused gather + self-loop + bias (+relu): wave per node, 8-deep MLP ----------
template <int NW, bool RELU>
__global__ __launch_bounds__(256) void gather_kernel(const int* __restrict__ rowptr,
                                                     const unsigned short* __restrict__ srcs,
                                                     const float* __restrict__ dinv,
                                                     const unsigned short* __restrict__ h,
                                                     const float* __restrict__ b,
                                                     float* __restrict__ out, int M) {
    constexpr int VEC = NW / 64;
    const int lane = threadIdx.x & 63;
    const int wid  = threadIdx.x >> 6;
    const int t    = blockIdx.x * 4 + wid;
    if (t >= M) return;

    float acc0 = 0.f, acc1 = 0.f;
    const int beg = rowptr[t], end = rowptr[t + 1];
    for (int eb = beg; eb < end; eb += 64) {
        const int rem = end - eb;
        int   sv = 0;
        float wv = 0.f;
        if (lane < rem) { sv = (int)srcs[eb + lane]; wv = dinv[sv]; }
        const int m = rem < 64 ? rem : 64;
        int j = 0;
        // 8-way unrolled: issue 8 independent row loads, then consume
        for (; j + 8 <= m; j += 8) {
            int   s[8];
            float w[8];
#pragma unroll
            for (int q = 0; q < 8; q++) { s[q] = __shfl(sv, j + q); w[q] = __shfl(wv, j + q); }
            if constexpr (VEC == 2) {
                unsigned int hv[8];
#pragma unroll
                for (int q = 0; q < 8; q++)
                    hv[q] = *reinterpret_cast<const unsigned int*>(h + (size_t)s[q] * NW + lane * 2);
#pragma unroll
                for (int q = 0; q < 8; q++) {
                    acc0 += w[q] * bfu_to_f(hv[q] & 0xffffu);
                    acc1 += w[q] * bfu_to_f(hv[q] >> 16);
                }
            } else {
                unsigned short hv[8];
#pragma unroll
                for (int q = 0; q < 8; q++) hv[q] = h[(size_t)s[q] * NW + lane];
#pragma unroll
                for (int q = 0; q < 8; q++) acc0 += w[q] * bfu_to_f(hv[q]);
            }
        }
        for (; j < m; j++) {
            int   s = __shfl(sv, j);
            float w = __shfl(wv, j);
            if constexpr (VEC == 2) {
                unsigned int hv = *reinterpret_cast<const unsigned int*>(
                    h + (size_t)s * NW + lane * 2);
                acc0 += w * bfu_to_f(hv & 0xffffu);
                acc1 += w * bfu_to_f(hv >> 16);
            } else {
                acc0 += w * bfu_to_f(h[(size_t)s * NW + lane]);
            }
        }
    }
    const float di = dinv[t];
    float* op = out + (size_t)t * NW + lane * VEC;
    if constexpr (VEC == 2) {
        unsigned int hv = *reinterpret_cast<const unsigned int*>(
            h + (size_t)t * NW + lane * 2);
        float2 bv = *reinterpret_cast<const float2*>(b + lane * 2);
        float v0 = acc0 * di + bfu_to_f(hv & 0xffffu) * di * di + bv.x;
        float v1 = acc1 * di + bfu_to_f(hv >> 16) * di * di + bv.y;
        if (RELU) { v0 = fmaxf(v0, 0.f); v1 = fmaxf(v1, 0.f); }
        *reinterpret_cast<float2*>(op) = make_float2(v0, v1);
    } else {
        float hs = bfu_to_f(h[(size_t)t * NW + lane]);
        float v0 = acc0 * di + hs * di * di + b[lane];
        if (RELU) v0 = fmaxf(v0, 0.f);
        op[0] = v0;
    }
}

extern "C" void kernel_launch(void* const* d_in, const int* in_sizes, int n_in,
                              void* d_out, int out_size, void* d_ws, size_t ws_size,
                              hipStream_t stream) {
    const float* x  = (const float*)d_in[0];
    const int*   ei = (const int*)d_in[1];
    const float* W1 = (const float*)d_in[2];
    const float* b1 = (const float*)d_in[3];
    const float* W2 = (const float*)d_in[4];
    const float* b2 = (const float*)d_in[5];

    float* out_h2 = (float*)d_out;                 // [NN x 64]
    float* out_h1 = out_h2 + (size_t)NN * 64;      // [NN x 128]

    const int* src = ei;
    const int* dst = ei + NE;

    // ws layout (4B words), ~21.5 MB of 256 MiB:
    int*   wsw    = (int*)d_ws;
    int*   cnt    = wsw;                        // 8*NN2 = 400384
    int*   deg    = wsw + 400384;               // 50048
    int*   rowptr = wsw + 450432;               // 50064
    float* dinv   = (float*)(wsw + 500496);     // 50048
    int*   bsum   = wsw + 550544;               // 64
    int*   boff   = wsw + 550608;               // 64
    int*   pos    = wsw + 550672;               // 800000
    int*   roff   = wsw + 1350672;              // 8*NN2 = 400384
    unsigned short* srcs = (unsigned short*)(wsw + 1751056);  // u16 [NE]
    unsigned short* T    = (unsigned short*)(wsw + 2151056);  // bf16 [NN x 128]

    // ----- fused: layer-1 GEMM (both chunks) + replicated rank histogram -----
    hipMemsetAsync(cnt, 0, 8 * NN2 * sizeof(int), stream);
    fused_gemm1_rank<<<RANK_BASE + RANK_BLOCKS, 256, 0, stream>>>(
        x, W1, T, dst, cnt, pos);

    // ----- CSR: reduce replicas -> scan -> place (atomic-free) -----
    reduce_kernel<<<NB, 256, 0, stream>>>(cnt, deg, roff, dinv, bsum, NN);
    scan_tops<<<1, 64, 0, stream>>>(bsum, boff, rowptr + NN, NB);
    scan_fill<<<NB, 256, 0, stream>>>(deg, boff, rowptr, NN);
    place_kernel<<<RANK_BLOCKS, 256, 0, stream>>>(src, dst, rowptr, roff, pos, srcs, NE);

    const int aB = (NN + 3) / 4;

    // ----- layer 1 gather -----
    gather_kernel<128, true><<<aB, 256, 0, stream>>>(rowptr, srcs, dinv, T,
                                                     b1, out_h1, NN);
    // ----- layer 2 -----
    gemm_kernel<128, 64, 64, 64><<<GB, 256, 0, stream>>>(out_h1, W2, 0, 0, T, NN);
    gather_kernel<64, false><<<aB, 256, 0, stream>>>(rowptr, srcs, dinv, T,
                                                     b2, out_h2, NN);
}